// Round 1
// baseline (49.326 us; speedup 1.0000x reference)
//
#include <hip/hip_runtime.h>

// kp_loss: result = sum_{b,k} exp(-||out[b,k]-tgt[b,k]||^2 / 2) / B
// B=8192, K=2048 -> 16.7M keypoints, 268 MB input, scalar output.
// Pure HBM-bandwidth-bound reduction.

#define KP_B 8192

__global__ __launch_bounds__(256) void kp_partial_kernel(
    const float4* __restrict__ out4,
    const float4* __restrict__ tgt4,
    float* __restrict__ partial,
    int n4)
{
    int tid = blockIdx.x * blockDim.x + threadIdx.x;
    int stride = gridDim.x * blockDim.x;

    float acc = 0.0f;
    for (int i = tid; i < n4; i += stride) {
        float4 o = out4[i];
        float4 t = tgt4[i];
        float dx0 = o.x - t.x, dy0 = o.y - t.y;
        float dx1 = o.z - t.z, dy1 = o.w - t.w;
        float s0 = dx0 * dx0 + dy0 * dy0;
        float s1 = dx1 * dx1 + dy1 * dy1;
        acc += __expf(-0.5f * s0);
        acc += __expf(-0.5f * s1);
    }

    // wave-64 butterfly reduce
    #pragma unroll
    for (int off = 32; off > 0; off >>= 1)
        acc += __shfl_down(acc, off, 64);

    __shared__ float wsum[4];
    int lane = threadIdx.x & 63;
    int wave = threadIdx.x >> 6;
    if (lane == 0) wsum[wave] = acc;
    __syncthreads();
    if (threadIdx.x == 0) {
        partial[blockIdx.x] = wsum[0] + wsum[1] + wsum[2] + wsum[3];
    }
}

__global__ __launch_bounds__(256) void kp_final_kernel(
    const float* __restrict__ partial,
    float* __restrict__ result,
    int n)
{
    float acc = 0.0f;
    for (int i = threadIdx.x; i < n; i += 256)
        acc += partial[i];

    #pragma unroll
    for (int off = 32; off > 0; off >>= 1)
        acc += __shfl_down(acc, off, 64);

    __shared__ float wsum[4];
    int lane = threadIdx.x & 63;
    int wave = threadIdx.x >> 6;
    if (lane == 0) wsum[wave] = acc;
    __syncthreads();
    if (threadIdx.x == 0) {
        result[0] = (wsum[0] + wsum[1] + wsum[2] + wsum[3]) * (1.0f / (float)KP_B);
    }
}

extern "C" void kernel_launch(void* const* d_in, const int* in_sizes, int n_in,
                              void* d_out, int out_size, void* d_ws, size_t ws_size,
                              hipStream_t stream)
{
    const float4* out4 = (const float4*)d_in[0];
    const float4* tgt4 = (const float4*)d_in[1];
    float* result = (float*)d_out;
    float* partial = (float*)d_ws;

    const int n_floats = in_sizes[0];          // 8192*2048*2 = 33,554,432
    const int n4 = n_floats / 4;               // 8,388,608 float4 pairs

    const int block = 256;
    const int grid = 2048;                     // 8 blocks/CU, grid-stride rest

    kp_partial_kernel<<<grid, block, 0, stream>>>(out4, tgt4, partial, n4);
    kp_final_kernel<<<1, block, 0, stream>>>(partial, result, grid);
}